// Round 15
// baseline (392.931 us; speedup 1.0000x reference)
//
#include <hip/hip_runtime.h>
#include <stdint.h>

// Residual VQ, MI355X. N=16384 rows, D=256, K=4096 codes, Q=4 stages.
// residual value never changes => all stages quantize zn=l2norm(x).
// Score: A(zn) RESIDENT in static LDS (4 slices, 64KB, staged once) +
// B double-buffer (32KB) = 96KB -> 1 block/CU, VGPR budget 512 (no spill
// risk); per-phase staging halves (B only). Read-first phase order proven
// in r8. margin flag -> K-chunk(16)-parallel 3-pass hi/lo MFMA rescue;
// ultra-tie -> parallel exact fp32 chain-dot scan (r1-r14 numerics) + valve.

#define NR 16384
#define DIM 256
#define KCB 4096
#define QST 4
#define MARGIN_DOT 4e-4f
#define MARGIN2_DOT 2e-5f
#define CAPL 4096

typedef _Float16 f16;
typedef __attribute__((ext_vector_type(4))) f16 f16x4;
typedef __attribute__((ext_vector_type(8))) f16 f16x8;
typedef __attribute__((ext_vector_type(4))) float f32x4;

// ---- workspace byte offsets (~41 MB) ----
#define WS_ZN_HI   ((size_t)0)                        // NR*DIM f16 = 8 MB
#define WS_ZN_LO   ((size_t)8*1024*1024)
#define WS_CB_HI   ((size_t)16*1024*1024)             // Q*K*DIM f16 = 8 MB
#define WS_CB_LO   ((size_t)24*1024*1024)
#define WS_NORMS   ((size_t)32*1024*1024)             // NR f32 (64KB)
#define WS_SSQ     (WS_NORMS + 65536)                 // Q*K f32 (64KB)
#define WS_TOPS    (WS_SSQ + 65536)                   // (unused; keeps layout)
#define WS_IDX     (WS_TOPS + (size_t)QST*NR*2*16)    // NR*Q int (256KB)
#define WS_LIST    (WS_IDX + (size_t)QST*NR*4)        // 4 x CAPL ints (64KB)
#define WS_LIST2   (WS_LIST + (size_t)QST*CAPL*4)     // 4 x NR ints (256KB)
#define WS_TOPS2   (WS_LIST2 + (size_t)QST*NR*4)      // 4*CAPL*16 float4 = 4 MB
#define WS_CNT     (WS_TOPS2 + (size_t)QST*CAPL*16*16) // 8 counters
#define WS_PART    (WS_CNT + 64)                      // 4096 f32 loss partials
#define WS_TOPS3   (WS_PART + 16384)                  // 4*CAPL*16 int2 = 2 MB

__device__ __forceinline__ void gll16(const void* g, void* l) {
  __builtin_amdgcn_global_load_lds(
      (const __attribute__((address_space(1))) void*)g,
      (__attribute__((address_space(3))) void*)l, 16, 0, 0);
}

// shared exact-dot helper: identical accumulation order as rounds 1-14
__device__ __forceinline__ float dot4chain(const float4* __restrict__ c,
                                           const float4* __restrict__ z) {
  float dot = 0.f;
  for (int d = 0; d < 64; ++d) {
    const float4 cv = c[d], zv = z[d];
    dot += cv.x * zv.x + cv.y * zv.y + cv.z * zv.z + cv.w * zv.w;
  }
  return dot;
}

// ---- prep: per-row sumsq (+l2norm for x), fp16 hi/lo split ----
__global__ void prep_kernel(const float* __restrict__ x, const float* __restrict__ cb,
                            char* __restrict__ ws) {
  const int w = threadIdx.x >> 6, lane = threadIdx.x & 63;
  const int normalize = (blockIdx.x < (NR / 4));
  const int blk = normalize ? blockIdx.x : blockIdx.x - (NR / 4);
  const float* src = normalize ? x : cb;
  const int row = blk * 4 + w;
  const float4 v = ((const float4*)src)[row * 64 + lane];
  float ss = v.x * v.x + v.y * v.y + v.z * v.z + v.w * v.w;
#pragma unroll
  for (int m = 32; m; m >>= 1) ss += __shfl_xor(ss, m);
  float4 z = v;
  f16 *hi, *lo;
  if (normalize) {
    const float denom = fmaxf(sqrtf(ss), 1e-12f);
    z.x = v.x / denom; z.y = v.y / denom; z.z = v.z / denom; z.w = v.w / denom;
    hi = (f16*)(ws + WS_ZN_HI); lo = (f16*)(ws + WS_ZN_LO);
    if (lane == 0) ((float*)(ws + WS_NORMS))[row] = denom;
    if (blockIdx.x == 0 && threadIdx.x < 8) ((int*)(ws + WS_CNT))[threadIdx.x] = 0;
  } else {
    hi = (f16*)(ws + WS_CB_HI); lo = (f16*)(ws + WS_CB_LO);
    if (lane == 0) ((float*)(ws + WS_SSQ))[row] = ss;
  }
  f16x4 h, l;
  h[0] = (f16)z.x; h[1] = (f16)z.y; h[2] = (f16)z.z; h[3] = (f16)z.w;
  l[0] = (f16)(z.x - (float)h[0]); l[1] = (f16)(z.y - (float)h[1]);
  l[2] = (f16)(z.z - (float)h[2]); l[3] = (f16)(z.w - (float)h[3]);
  ((f16x4*)hi)[row * 64 + lane] = h;
  ((f16x4*)lo)[row * 64 + lane] = l;
}

// ---- score: A-resident LDS + B dbuf, read-first phases, ungated top-2 ----
__launch_bounds__(256, 1)
__global__ void score_kernel(char* __restrict__ ws) {
  // A resident: 4 dc slices (64KB); B double-buffer (32KB). Total 96KB.
  __shared__ __align__(16) f16 Astat0[128][64];
  __shared__ __align__(16) f16 Astat1[128][64];
  __shared__ __align__(16) f16 Astat2[128][64];
  __shared__ __align__(16) f16 Astat3[128][64];
  __shared__ __align__(16) f16 Bb0[128][64];
  __shared__ __align__(16) f16 Bb1[128][64];
  const int tid = threadIdx.x, w = tid >> 6, lane = tid & 63;
  const int wr = w >> 1, wc = w & 1;
  const int blk = blockIdx.x;
  const int xcd = blk & 7, st = xcd >> 1;
  const int rowtile = ((xcd & 1) << 6) + (blk >> 3);
  const int rowBase = rowtile << 7;

  const f16* zn_hi = (const f16*)(ws + WS_ZN_HI);
  const f16* cb_hi = (const f16*)(ws + WS_CB_HI);

  const int reg = w >> 1;            // prologue role: 0 = stage A, 1 = stage B
  const int half = w & 1;            // which 64-row half of the tile
  // pre-swizzled global source: LDS[row][slot] holds granule (slot ^ (row&7))
  const int g0 = (lane & 7) ^ ((lane >> 3) & 7);
  const size_t laneOff = (size_t)(lane >> 3) * DIM + (size_t)g0 * 8;
  const f16* srcA0 = zn_hi + (size_t)(rowBase + half * 64) * DIM + laneOff;
  const f16* srcB0 = cb_hi + ((size_t)st * KCB + half * 64) * DIM + laneOff;
  // main-loop B staging: each wave stages a 32-row quarter of the next slice
  const f16* srcBq0 = cb_hi + ((size_t)st * KCB + w * 32) * DIM + laneOff;

  float t1[16], t2[16]; int i1[16];
#pragma unroll
  for (int s = 0; s < 16; ++s) { t1[s] = -3.4e38f; t2[s] = -3.4e38f; i1[s] = 0; }
  const int colLane = wc * 64 + (lane & 15);

  // ---- prologue: A-waves stage all 4 resident A slices; B-waves stage B(0,0)
  if (reg == 0) {
#pragma unroll
    for (int dc = 0; dc < 4; ++dc) {
      f16* ad = (dc == 0) ? &Astat0[half * 64][0]
              : (dc == 1) ? &Astat1[half * 64][0]
              : (dc == 2) ? &Astat2[half * 64][0]
                          : &Astat3[half * 64][0];
      const f16* sp = srcA0 + dc * 64;
#pragma unroll
      for (int op = 0; op < 8; ++op)
        gll16(sp + op * 8 * DIM, ad + op * 512);
    }
  } else {
#pragma unroll
    for (int op = 0; op < 8; ++op)
      gll16(srcB0 + op * 8 * DIM, &Bb0[half * 64][0] + op * 512);
  }
  __syncthreads();

  f32x4 acc[4][4];
  const f32x4 zero4 = {0.f, 0.f, 0.f, 0.f};

  // 4 gll16 per wave: stage this wave's 32-row quarter of a B slice
  auto STAGE4 = [&](f16* dst, const f16* sp) {
#pragma unroll
    for (int op = 0; op < 4; ++op)
      gll16(sp + op * 8 * DIM, dst + op * 512);
  };

  // one phase: read frags (ds_read) -> stage next B slice -> MFMA -> barrier
  auto PHASE = [&](const f16* As, const f16* Bs, f16* stDst, const f16* stSrc,
                   bool doStage, bool init) {
    f16x8 ah[2][4], bh[2][4];
#pragma unroll
    for (int kk = 0; kk < 2; ++kk) {
#pragma unroll
      for (int m = 0; m < 4; ++m) {
        const int rl = wr * 64 + m * 16 + (lane & 15);
        const int slot = ((kk << 2) + (lane >> 4)) ^ (rl & 7);
        ah[kk][m] = *(const f16x8*)(As + rl * 64 + slot * 8);
      }
#pragma unroll
      for (int n = 0; n < 4; ++n) {
        const int cl = wc * 64 + n * 16 + (lane & 15);
        const int slot = ((kk << 2) + (lane >> 4)) ^ (cl & 7);
        bh[kk][n] = *(const f16x8*)(Bs + cl * 64 + slot * 8);
      }
    }
    if (doStage) STAGE4(stDst, stSrc);
#pragma unroll
    for (int kk = 0; kk < 2; ++kk)
#pragma unroll
      for (int n = 0; n < 4; ++n) {
        if (init && kk == 0) {
#pragma unroll
          for (int m = 0; m < 4; ++m)
            acc[m][n] = __builtin_amdgcn_mfma_f32_16x16x32_f16(ah[0][m], bh[0][n], zero4, 0, 0, 0);
        } else {
#pragma unroll
          for (int m = 0; m < 4; ++m)
            acc[m][n] = __builtin_amdgcn_mfma_f32_16x16x32_f16(ah[kk][m], bh[kk][n], acc[m][n], 0, 0, 0);
        }
      }
    __syncthreads();
  };

  for (int ct = 0; ct < 32; ++ct) {
    const f16* sB = srcBq0 + (size_t)ct * 128 * DIM;
    PHASE(&Astat0[0][0], &Bb0[0][0], &Bb1[w * 32][0], sB + 1 * 64, true, true);
    PHASE(&Astat1[0][0], &Bb1[0][0], &Bb0[w * 32][0], sB + 2 * 64, true, false);
    PHASE(&Astat2[0][0], &Bb0[0][0], &Bb1[w * 32][0], sB + 3 * 64, true, false);
    PHASE(&Astat3[0][0], &Bb1[0][0], &Bb0[w * 32][0], sB + (size_t)128 * DIM, ct < 31, false);
    // rank by raw dot (codebook unit-norm => ssq const to ~1e-7 << margin)
#pragma unroll
    for (int n = 0; n < 4; ++n) {
      const int col = ct * 128 + n * 16 + colLane;
#pragma unroll
      for (int m = 0; m < 4; ++m)
#pragma unroll
        for (int rr = 0; rr < 4; ++rr) {
          const float sc = acc[m][n][rr];
          const int sl = m * 4 + rr;
          if (sc > t1[sl]) { t2[sl] = t1[sl]; t1[sl] = sc; i1[sl] = col; }
          else t2[sl] = fmaxf(t2[sl], sc);
        }
    }
  }

  // epilogue: butterfly within 16-lane groups, then cross-half merge in LDS
  float* mv1 = (float*)&Astat0[0][0];  // [2][128], aliases dead buffer
  float* mv2 = mv1 + 256;
  int*   mi1v = (int*)(mv2 + 256);
#pragma unroll
  for (int m = 0; m < 4; ++m)
#pragma unroll
    for (int rr = 0; rr < 4; ++rr) {
      const int sl = m * 4 + rr;
      float a1 = t1[sl], a2 = t2[sl]; int ai = i1[sl];
#pragma unroll
      for (int msk = 1; msk < 16; msk <<= 1) {
        const float o1 = __shfl_xor(a1, msk);
        const float o2 = __shfl_xor(a2, msk);
        const int   oi = __shfl_xor(ai, msk);
        if (o1 > a1)       { a2 = fmaxf(a1, o2); a1 = o1; ai = oi; }
        else if (o1 == a1) { a2 = a1; ai = min(ai, oi); }
        else               { a2 = fmaxf(a2, o1); }
      }
      if ((lane & 15) == 0) {
        const int rloc = wr * 64 + m * 16 + (lane >> 4) * 4 + rr;
        mv1[wc * 128 + rloc] = a1; mv2[wc * 128 + rloc] = a2; mi1v[wc * 128 + rloc] = ai;
      }
    }
  __syncthreads();
  if (tid < 128) {
    const float a1 = mv1[tid], a2 = mv2[tid]; const int ai = mi1v[tid];
    const float b1 = mv1[128 + tid], b2 = mv2[128 + tid]; const int bi = mi1v[128 + tid];
    float v1, v2; int fi;
    if (a1 > b1)      { v1 = a1; v2 = fmaxf(a2, b1); fi = ai; }
    else if (b1 > a1) { v1 = b1; v2 = fmaxf(b2, a1); fi = bi; }
    else { v1 = a1; v2 = a1; fi = min(ai, bi); }
    const int row = rowBase + tid;
    ((int*)(ws + WS_IDX))[row * 4 + st] = fi;
    if (v1 - v2 < MARGIN_DOT) {
      const int p = atomicAdd((int*)(ws + WS_CNT) + st, 1);
      if (p < CAPL) ((int*)(ws + WS_LIST))[st * CAPL + p] = row;
      else {  // overflow valve: route straight to exact full-scan (no drop)
        const int p2 = atomicAdd((int*)(ws + WS_CNT) + 4 + st, 1);
        ((int*)(ws + WS_LIST2))[(size_t)st * NR + p2] = row;
      }
    }
  }
}

// ---- MFMA rescue: gather flagged rows, 3-pass hi/lo scan, 16 K-chunks ----
__launch_bounds__(256, 2)
__global__ void rescue_mfma_kernel(char* __restrict__ ws) {
  // [0]=A_hi [1]=A_lo [2]=B_hi [3]=B_lo, each [128 rows][64 halfs] = 64 KB
  __shared__ __align__(16) f16 smem[4][128][64];
  __shared__ float mv1[2][128], mv2[2][128];
  __shared__ int   mi1[2][128];
  const int tid = threadIdx.x, w = tid >> 6, lane = tid & 63;
  const int wr = w >> 1, wc = w & 1;
  const int st = blockIdx.x & 3;
  const int kc = (blockIdx.x >> 2) & 15;    // K-chunk: ct in [kc*2, kc*2+2)
  const int slot = blockIdx.x >> 6;         // 0..31 tile slot
  const int cnt = min(((const int*)(ws + WS_CNT))[st], CAPL);
  const int ntile = (cnt + 127) >> 7;
  const int* list = (const int*)(ws + WS_LIST) + st * CAPL;

  const f16* zn_hi = (const f16*)(ws + WS_ZN_HI);
  const f16* zn_lo = (const f16*)(ws + WS_ZN_LO);
  const f16* cb_hi = (const f16*)(ws + WS_CB_HI);
  const f16* cb_lo = (const f16*)(ws + WS_CB_LO);

  const int g0 = (lane & 7) ^ ((lane >> 3) & 7);
  const size_t laneOff = (size_t)(lane >> 3) * DIM + (size_t)g0 * 8;
  f16* ldsW = &smem[w][0][0];
  const f16* srcA = (w == 1) ? zn_lo : zn_hi;   // waves 0/1 stage A hi/lo
  const f16* srcB = (w == 3) ? cb_lo : cb_hi;   // waves 2/3 stage B hi/lo
  const int colLane = wc * 64 + (lane & 15);

  for (int tile = slot; tile < ntile; tile += 32) {
    const int base = tile << 7;
    int lid[16];
    if (w < 2) {
#pragma unroll
      for (int op = 0; op < 16; ++op) {
        const int i = base + op * 8 + (lane >> 3);
        lid[op] = list[min(i, cnt - 1)];
      }
    }
    float t1[16], t2[16]; int i1[16];
#pragma unroll
    for (int s = 0; s < 16; ++s) { t1[s] = -3.4e38f; t2[s] = -3.4e38f; i1[s] = 0; }

    for (int ct = kc * 2; ct < kc * 2 + 2; ++ct) {
      f32x4 acc[4][4];
#pragma unroll
      for (int m = 0; m < 4; ++m)
#pragma unroll
        for (int n = 0; n < 4; ++n) { acc[m][n][0] = 0.f; acc[m][n][1] = 0.f; acc[m][n][2] = 0.f; acc[m][n][3] = 0.f; }

      const f16* srcBBase = srcB + ((size_t)st * KCB + (size_t)ct * 128) * DIM + laneOff;

      for (int dc = 0; dc < 4; ++dc) {
        __syncthreads();
        if (w < 2) {
#pragma unroll
          for (int op = 0; op < 16; ++op)
            gll16(srcA + (size_t)lid[op] * DIM + dc * 64 + (size_t)g0 * 8,
                  ldsW + op * 512);
        } else {
          const f16* sp = srcBBase + dc * 64;
#pragma unroll
          for (int op = 0; op < 16; ++op)
            gll16(sp + op * 8 * DIM, ldsW + op * 512);
        }
        __syncthreads();

#pragma unroll
        for (int kk = 0; kk < 2; ++kk) {
          f16x8 ah[4], al[4];
#pragma unroll
          for (int m = 0; m < 4; ++m) {
            const int rl = wr * 64 + m * 16 + (lane & 15);
            const int slt = ((kk << 2) + (lane >> 4)) ^ (rl & 7);
            const int off = rl * 64 + slt * 8;
            ah[m] = *(const f16x8*)(&smem[0][0][0] + off);
            al[m] = *(const f16x8*)(&smem[1][0][0] + off);
          }
#pragma unroll
          for (int n = 0; n < 4; ++n) {
            const int cl = wc * 64 + n * 16 + (lane & 15);
            const int slt = ((kk << 2) + (lane >> 4)) ^ (cl & 7);
            const int off = cl * 64 + slt * 8;
            const f16x8 bh = *(const f16x8*)(&smem[2][0][0] + off);
            const f16x8 bl = *(const f16x8*)(&smem[3][0][0] + off);
#pragma unroll
            for (int m = 0; m < 4; ++m) {
              acc[m][n] = __builtin_amdgcn_mfma_f32_16x16x32_f16(ah[m], bh, acc[m][n], 0, 0, 0);
              acc[m][n] = __builtin_amdgcn_mfma_f32_16x16x32_f16(ah[m], bl, acc[m][n], 0, 0, 0);
              acc[m][n] = __builtin_amdgcn_mfma_f32_16x16x32_f16(al[m], bh, acc[m][n], 0, 0, 0);
            }
          }
        }
      }
#pragma unroll
      for (int n = 0; n < 4; ++n) {
        const int col = ct * 128 + n * 16 + colLane;
#pragma unroll
        for (int m = 0; m < 4; ++m)
#pragma unroll
          for (int r = 0; r < 4; ++r) {
            const float sc = acc[m][n][r];
            const int sl = m * 4 + r;
            if (sc > t1[sl]) { t2[sl] = t1[sl]; t1[sl] = sc; i1[sl] = col; }
            else t2[sl] = fmaxf(t2[sl], sc);
          }
      }
    }

    // butterfly merge across 16 lanes -> LDS merge buffers
#pragma unroll
    for (int m = 0; m < 4; ++m)
#pragma unroll
      for (int r = 0; r < 4; ++r) {
        const int sl = m * 4 + r;
        float a1 = t1[sl], a2 = t2[sl]; int ai = i1[sl];
#pragma unroll
        for (int msk = 1; msk < 16; msk <<= 1) {
          const float o1 = __shfl_xor(a1, msk);
          const float o2 = __shfl_xor(a2, msk);
          const int   oi = __shfl_xor(ai, msk);
          if (o1 > a1)       { a2 = fmaxf(a1, o2); a1 = o1; ai = oi; }
          else if (o1 == a1) { a2 = a1; ai = min(ai, oi); }
          else               { a2 = fmaxf(a2, o1); }
        }
        if ((lane & 15) == 0) {
          const int rloc = wr * 64 + m * 16 + (lane >> 4) * 4 + r;
          mv1[wc][rloc] = a1; mv2[wc][rloc] = a2; mi1[wc][rloc] = ai;
        }
      }
    __syncthreads();
    if (tid < 128 && base + tid < cnt) {
      const float a1 = mv1[0][tid], a2 = mv2[0][tid]; const int ai = mi1[0][tid];
      const float b1 = mv1[1][tid], b2 = mv2[1][tid]; const int bi = mi1[1][tid];
      float v1, v2; int fi;
      if (a1 > b1)      { v1 = a1; v2 = fmaxf(a2, b1); fi = ai; }
      else if (b1 > a1) { v1 = b1; v2 = fmaxf(b2, a1); fi = bi; }
      else { v1 = a1; v2 = a1; fi = min(ai, bi); }
      ((float4*)(ws + WS_TOPS2))[((size_t)(st * CAPL + base + tid) << 4) + kc] =
          make_float4(v1, v2, __int_as_float(fi), 0.f);
    }
    __syncthreads();
  }
}

// ---- merge 16 K-chunk partials per flagged row, flag ultra-ties ----
__global__ void rescue_merge_kernel(char* __restrict__ ws) {
  const int t = blockIdx.x * 256 + threadIdx.x;   // 4*CAPL entries
  const int st = t >> 12, j = t & (CAPL - 1);
  const int cnt = min(((const int*)(ws + WS_CNT))[st], CAPL);
  if (j >= cnt) return;
  const float4* p = (const float4*)(ws + WS_TOPS2) + ((size_t)(st * CAPL + j) << 4);
  float V1 = -3.4e38f, V2 = -3.4e38f; int I1 = 0;
#pragma unroll
  for (int c = 0; c < 16; ++c) {
    const float4 e = p[c];
    const float v1 = e.x, v2 = e.y; const int i1 = __float_as_int(e.z);
    if (v1 > V1) { V2 = fmaxf(V1, v2); V1 = v1; I1 = i1; }
    else {
      if (v1 == V1) I1 = min(I1, i1);
      V2 = fmaxf(V2, v1);
    }
  }
  const int row = ((const int*)(ws + WS_LIST))[st * CAPL + j];
  ((int*)(ws + WS_IDX))[row * 4 + st] = I1;
  if (V1 - V2 < MARGIN2_DOT) {
    const int p2 = atomicAdd((int*)(ws + WS_CNT) + 4 + st, 1);
    ((int*)(ws + WS_LIST2))[(size_t)st * NR + p2] = row;
  }
}

// ---- parallel exact fp32 chain-dot scan: one code/thread, 16 K-chunks ----
__global__ void rescue_exact_kernel(const float* __restrict__ x, const float* __restrict__ cb,
                                    char* __restrict__ ws) {
  __shared__ __align__(16) float zrow[DIM];
  __shared__ float zsq_s;
  __shared__ float lbv[4];
  __shared__ int   lbi[4];
  const int tid = threadIdx.x, w = tid >> 6, lane = tid & 63;
  const int st = blockIdx.x & 3;
  const int kc = (blockIdx.x >> 2) & 15;    // 16 K-chunks of 256 codes
  const int slot = blockIdx.x >> 6;         // 16 row slots
  const int cnt = min(((const int*)(ws + WS_CNT))[4 + st], CAPL);
  const int* list = (const int*)(ws + WS_LIST2) + (size_t)st * NR;
  const float* cbs = cb + (size_t)st * KCB * DIM;
  const float* ssqp = (const float*)(ws + WS_SSQ) + (size_t)st * KCB;
  int2* part = (int2*)(ws + WS_TOPS3);

  for (int j = slot; j < cnt; j += 16) {
    const int row = list[j];
    if (tid < 32) {
      const float denom = ((const float*)(ws + WS_NORMS))[row];
      const int g = tid;
      float ss = 0.f;
#pragma unroll
      for (int e = 0; e < 8; ++e) {
        const float v = x[(size_t)row * DIM + g * 8 + e] / denom;
        zrow[g * 8 + e] = v;
        ss += v * v;
      }
#pragma unroll
      for (int m = 16; m; m >>= 1) ss += __shfl_xor(ss, m);
      if (g == 0) zsq_s = ss;
    }
    __syncthreads();
    const float zsq = zsq_s;
    const int k = kc * 256 + tid;
    const float dot = dot4chain((const float4*)(cbs + (size_t)k * DIM), (const float4*)zrow);
    float bd = (zsq + ssqp[k]) - 2.0f * dot;
    int bi = k;
#pragma unroll
    for (int m = 32; m; m >>= 1) {
      const float od = __shfl_xor(bd, m);
      const int   oi = __shfl_xor(bi, m);
      if (od < bd || (od == bd && oi < bi)) { bd = od; bi = oi; }
    }
    if (lane == 0) { lbv[w] = bd; lbi[w] = bi; }
    __syncthreads();
    if (tid == 0) {
      float fb = lbv[0]; int fi = lbi[0];
#pragma unroll
      for (int ww = 1; ww < 4; ++ww)
        if (lbv[ww] < fb || (lbv[ww] == fb && lbi[ww] < fi)) { fb = lbv[ww]; fi = lbi[ww]; }
      part[((size_t)(st * CAPL + j) << 4) + kc] = make_int2(__float_as_int(fb), fi);
    }
    __syncthreads();
  }
}

// ---- fold 16 K-chunk partials per ultra-tie row ----
__global__ void rescue_exact_merge_kernel(char* __restrict__ ws) {
  const int t = blockIdx.x * 256 + threadIdx.x;   // 4*CAPL entries
  const int st = t >> 12, j = t & (CAPL - 1);
  const int cnt = min(((const int*)(ws + WS_CNT))[4 + st], CAPL);
  if (j >= cnt) return;
  const int2* part = (const int2*)(ws + WS_TOPS3) + ((size_t)(st * CAPL + j) << 4);
  float fb = 3.4e38f; int fi = 0x7fffffff;
#pragma unroll
  for (int kc = 0; kc < 16; ++kc) {
    const int2 e = part[kc];
    const float d = __int_as_float(e.x);
    if (d < fb || (d == fb && e.y < fi)) { fb = d; fi = e.y; }
  }
  const int row = ((const int*)(ws + WS_LIST2))[(size_t)st * NR + j];
  ((int*)(ws + WS_IDX))[row * 4 + st] = fi;
}

// ---- serial tail valve: ultra-tie rows beyond CAPL (empty in practice) ----
__global__ void rescue_tail_kernel(const float* __restrict__ x, const float* __restrict__ cb,
                                   char* __restrict__ ws) {
  __shared__ __align__(16) float zrows[8][DIM];
  __shared__ float zsqs[8];
  __shared__ float lbv[4][8];
  __shared__ int   lbi[4][8];
  const int tid = threadIdx.x, w = tid >> 6, lane = tid & 63;
  const int st = blockIdx.x & 3, slot = blockIdx.x >> 2;   // 16 slots/stage
  const int cnt = ((const int*)(ws + WS_CNT))[4 + st] - CAPL;
  if (cnt <= 0) return;
  const int nch = (cnt + 7) >> 3;
  const int* list = (const int*)(ws + WS_LIST2) + (size_t)st * NR + CAPL;
  const float* cbs = cb + (size_t)st * KCB * DIM;
  const float* ssqp = (const float*)(ws + WS_SSQ) + (size_t)st * KCB;

  for (int ch = slot; ch < nch; ch += 16) {
    const int base = ch * 8;
    const int nr = min(8, cnt - base);
    const int r = tid >> 5, g = tid & 31;
    if (r < nr) {
      const int row = list[base + r];
      const float denom = ((const float*)(ws + WS_NORMS))[row];
      float ss = 0.f;
#pragma unroll
      for (int j = 0; j < 8; ++j) {
        const float v = x[(size_t)row * DIM + g * 8 + j] / denom;
        zrows[r][g * 8 + j] = v;
        ss += v * v;
      }
#pragma unroll
      for (int m = 16; m; m >>= 1) ss += __shfl_xor(ss, m);
      if (g == 0) zsqs[r] = ss;
    }
    __syncthreads();

    float bd[8]; int bix[8];
#pragma unroll
    for (int q = 0; q < 8; ++q) { bd[q] = 3.4e38f; bix[q] = 0x7fffffff; }

    for (int k = tid; k < KCB; k += 256) {
      const float4* cr = (const float4*)(cbs + (size_t)k * DIM);
      const float4* zr = (const float4*)&zrows[0][0];
      float dot[8];
#pragma unroll
      for (int q = 0; q < 8; ++q) dot[q] = 0.f;
      for (int d = 0; d < 64; ++d) {
        const float4 cv = cr[d];
#pragma unroll
        for (int q = 0; q < 8; ++q) {
          const float4 zv = zr[q * 64 + d];
          dot[q] += cv.x * zv.x + cv.y * zv.y + cv.z * zv.z + cv.w * zv.w;
        }
      }
      const float sk = ssqp[k];
#pragma unroll
      for (int q = 0; q < 8; ++q) {
        const float dist = (zsqs[q] + sk) - 2.0f * dot[q];
        if (dist < bd[q]) { bd[q] = dist; bix[q] = k; }
      }
    }
#pragma unroll
    for (int q = 0; q < 8; ++q) {
#pragma unroll
      for (int m = 32; m; m >>= 1) {
        const float od = __shfl_xor(bd[q], m);
        const int   oi = __shfl_xor(bix[q], m);
        if (od < bd[q] || (od == bd[q] && oi < bix[q])) { bd[q] = od; bix[q] = oi; }
      }
      if (lane == 0) { lbv[w][q] = bd[q]; lbi[w][q] = bix[q]; }
    }
    __syncthreads();
    if (tid < 8 && tid < nr) {
      float fb = lbv[0][tid]; int fi = lbi[0][tid];
#pragma unroll
      for (int ww = 1; ww < 4; ++ww) {
        const float od = lbv[ww][tid]; const int oi = lbi[ww][tid];
        if (od < fb || (od == fb && oi < fi)) { fb = od; fi = oi; }
      }
      const int row = list[base + tid];
      ((int*)(ws + WS_IDX))[row * 4 + st] = fi;
    }
    __syncthreads();
  }
}

// ---- gather codewords, quantized sum, loss partials, indices(as float) ----
__global__ void finalize_kernel(const float* __restrict__ x, const float* __restrict__ cb,
                                char* __restrict__ ws, float* __restrict__ out) {
  __shared__ float wsum[4];
  const int w = threadIdx.x >> 6, lane = threadIdx.x & 63;
  const int row = blockIdx.x * 4 + w;
  const int* idxp = (const int*)(ws + WS_IDX) + (size_t)row * 4;
  const float denom = ((const float*)(ws + WS_NORMS))[row];
  const float4 xv = ((const float4*)x)[row * 64 + lane];
  const float4 zn = make_float4(xv.x / denom, xv.y / denom, xv.z / denom, xv.w / denom);
  float4 s = make_float4(0.f, 0.f, 0.f, 0.f);
  float lacc = 0.f;
#pragma unroll
  for (int q = 0; q < 4; ++q) {
    const int id = idxp[q];
    const float4 e = ((const float4*)(cb + ((size_t)q * KCB + id) * DIM))[lane];
    s.x += e.x; s.y += e.y; s.z += e.z; s.w += e.w;
    const float dx = e.x - zn.x, dy = e.y - zn.y, dz = e.z - zn.z, dw = e.w - zn.w;
    lacc += dx * dx + dy * dy + dz * dz + dw * dw;
  }
  ((float4*)out)[row * 64 + lane] = s;
  if (lane < 4) out[4194305 + (size_t)row * 4 + lane] = (float)idxp[lane];
#pragma unroll
  for (int m = 32; m; m >>= 1) lacc += __shfl_xor(lacc, m);
  if (lane == 0) wsum[w] = lacc;
  __syncthreads();
  if (threadIdx.x == 0)
    ((float*)(ws + WS_PART))[blockIdx.x] = wsum[0] + wsum[1] + wsum[2] + wsum[3];
}

__global__ void loss_final_kernel(const char* __restrict__ ws, float* __restrict__ out) {
  __shared__ float wsum[4];
  const int tid = threadIdx.x, w = tid >> 6, lane = tid & 63;
  const float* p = (const float*)(ws + WS_PART);
  float s = 0.f;
  for (int i = tid; i < 4096; i += 256) s += p[i];
#pragma unroll
  for (int m = 32; m; m >>= 1) s += __shfl_xor(s, m);
  if (lane == 0) wsum[w] = s;
  __syncthreads();
  if (tid == 0)
    out[4194304] = (wsum[0] + wsum[1] + wsum[2] + wsum[3]) * (1.0f / 4194304.0f);
}

extern "C" void kernel_launch(void* const* d_in, const int* in_sizes, int n_in,
                              void* d_out, int out_size, void* d_ws, size_t ws_size,
                              hipStream_t stream) {
  (void)in_sizes; (void)n_in; (void)out_size; (void)ws_size;
  const float* x = (const float*)d_in[0];
  const float* cb = (const float*)d_in[1];
  float* out = (float*)d_out;
  char* ws = (char*)d_ws;

  hipLaunchKernelGGL(prep_kernel, dim3(NR / 2), dim3(256), 0, stream, x, cb, ws);
  hipLaunchKernelGGL(score_kernel, dim3(512), dim3(256), 0, stream, ws);
  hipLaunchKernelGGL(rescue_mfma_kernel, dim3(2048), dim3(256), 0, stream, ws);
  hipLaunchKernelGGL(rescue_merge_kernel, dim3((QST * CAPL) / 256), dim3(256), 0, stream, ws);
  hipLaunchKernelGGL(rescue_exact_kernel, dim3(1024), dim3(256), 0, stream, x, cb, ws);
  hipLaunchKernelGGL(rescue_exact_merge_kernel, dim3((QST * CAPL) / 256), dim3(256), 0, stream, ws);
  hipLaunchKernelGGL(rescue_tail_kernel, dim3(64), dim3(256), 0, stream, x, cb, ws);
  hipLaunchKernelGGL(finalize_kernel, dim3(NR / 4), dim3(256), 0, stream, x, cb, ws, out);
  hipLaunchKernelGGL(loss_final_kernel, dim3(1), dim3(256), 0, stream, ws, out);
}

// Round 16
// 337.605 us; speedup vs baseline: 1.1639x; 1.1639x over previous
//
#include <hip/hip_runtime.h>
#include <stdint.h>

// Residual VQ, MI355X. N=16384 rows, D=256, K=4096 codes, Q=4 stages.
// residual value never changes => all stages quantize zn=l2norm(x).
// FINAL (round-11/14 best, 338.6us): round-8 proven score (static-dbuf
// read-first pipeline, ungated top-2, VGPR 108, 2 blocks/CU); margin flag ->
// K-chunk(16)-parallel 3-pass hi/lo MFMA rescue; ultra-tie -> parallel
// exact fp32 chain-dot scan (numerics identical to r1-r15) + tail valve.
// Dead ends (measured): dbuf alone +0%, gated top-2 -17%, A-in-regs spill,
// wave-specialization spill x2, A-resident-LDS -50% (1 blk/CU kills the
// implicit cross-block latency hiding; A re-reads were L2-hits anyway).

#define NR 16384
#define DIM 256
#define KCB 4096
#define QST 4
#define MARGIN_DOT 4e-4f
#define MARGIN2_DOT 2e-5f
#define CAPL 4096

typedef _Float16 f16;
typedef __attribute__((ext_vector_type(4))) f16 f16x4;
typedef __attribute__((ext_vector_type(8))) f16 f16x8;
typedef __attribute__((ext_vector_type(4))) float f32x4;

// ---- workspace byte offsets (~41 MB) ----
#define WS_ZN_HI   ((size_t)0)                        // NR*DIM f16 = 8 MB
#define WS_ZN_LO   ((size_t)8*1024*1024)
#define WS_CB_HI   ((size_t)16*1024*1024)             // Q*K*DIM f16 = 8 MB
#define WS_CB_LO   ((size_t)24*1024*1024)
#define WS_NORMS   ((size_t)32*1024*1024)             // NR f32 (64KB)
#define WS_SSQ     (WS_NORMS + 65536)                 // Q*K f32 (64KB)
#define WS_TOPS    (WS_SSQ + 65536)                   // (unused; keeps layout)
#define WS_IDX     (WS_TOPS + (size_t)QST*NR*2*16)    // NR*Q int (256KB)
#define WS_LIST    (WS_IDX + (size_t)QST*NR*4)        // 4 x CAPL ints (64KB)
#define WS_LIST2   (WS_LIST + (size_t)QST*CAPL*4)     // 4 x NR ints (256KB)
#define WS_TOPS2   (WS_LIST2 + (size_t)QST*NR*4)      // 4*CAPL*16 float4 = 4 MB
#define WS_CNT     (WS_TOPS2 + (size_t)QST*CAPL*16*16) // 8 counters
#define WS_PART    (WS_CNT + 64)                      // 4096 f32 loss partials
#define WS_TOPS3   (WS_PART + 16384)                  // 4*CAPL*16 int2 = 2 MB

__device__ __forceinline__ void gll16(const void* g, void* l) {
  __builtin_amdgcn_global_load_lds(
      (const __attribute__((address_space(1))) void*)g,
      (__attribute__((address_space(3))) void*)l, 16, 0, 0);
}

// shared exact-dot helper: identical accumulation order as rounds 1-15
__device__ __forceinline__ float dot4chain(const float4* __restrict__ c,
                                           const float4* __restrict__ z) {
  float dot = 0.f;
  for (int d = 0; d < 64; ++d) {
    const float4 cv = c[d], zv = z[d];
    dot += cv.x * zv.x + cv.y * zv.y + cv.z * zv.z + cv.w * zv.w;
  }
  return dot;
}

// ---- prep: per-row sumsq (+l2norm for x), fp16 hi/lo split ----
__global__ void prep_kernel(const float* __restrict__ x, const float* __restrict__ cb,
                            char* __restrict__ ws) {
  const int w = threadIdx.x >> 6, lane = threadIdx.x & 63;
  const int normalize = (blockIdx.x < (NR / 4));
  const int blk = normalize ? blockIdx.x : blockIdx.x - (NR / 4);
  const float* src = normalize ? x : cb;
  const int row = blk * 4 + w;
  const float4 v = ((const float4*)src)[row * 64 + lane];
  float ss = v.x * v.x + v.y * v.y + v.z * v.z + v.w * v.w;
#pragma unroll
  for (int m = 32; m; m >>= 1) ss += __shfl_xor(ss, m);
  float4 z = v;
  f16 *hi, *lo;
  if (normalize) {
    const float denom = fmaxf(sqrtf(ss), 1e-12f);
    z.x = v.x / denom; z.y = v.y / denom; z.z = v.z / denom; z.w = v.w / denom;
    hi = (f16*)(ws + WS_ZN_HI); lo = (f16*)(ws + WS_ZN_LO);
    if (lane == 0) ((float*)(ws + WS_NORMS))[row] = denom;
    if (blockIdx.x == 0 && threadIdx.x < 8) ((int*)(ws + WS_CNT))[threadIdx.x] = 0;
  } else {
    hi = (f16*)(ws + WS_CB_HI); lo = (f16*)(ws + WS_CB_LO);
    if (lane == 0) ((float*)(ws + WS_SSQ))[row] = ss;
  }
  f16x4 h, l;
  h[0] = (f16)z.x; h[1] = (f16)z.y; h[2] = (f16)z.z; h[3] = (f16)z.w;
  l[0] = (f16)(z.x - (float)h[0]); l[1] = (f16)(z.y - (float)h[1]);
  l[2] = (f16)(z.z - (float)h[2]); l[3] = (f16)(z.w - (float)h[3]);
  ((f16x4*)hi)[row * 64 + lane] = h;
  ((f16x4*)lo)[row * 64 + lane] = l;
}

// ---- score: 1-pass hi*hi GEMM, static-dbuf read-first pipeline (r8 exact) ----
__launch_bounds__(256, 2)
__global__ void score_kernel(char* __restrict__ ws) {
  // four DISTINCT shared objects: compile-time disjoint => no alias waits
  __shared__ __align__(16) f16 A0[128][64];
  __shared__ __align__(16) f16 A1[128][64];
  __shared__ __align__(16) f16 B0[128][64];
  __shared__ __align__(16) f16 B1[128][64];
  const int tid = threadIdx.x, w = tid >> 6, lane = tid & 63;
  const int wr = w >> 1, wc = w & 1;
  const int blk = blockIdx.x;
  const int xcd = blk & 7, st = xcd >> 1;
  const int rowtile = ((xcd & 1) << 6) + (blk >> 3);
  const int rowBase = rowtile << 7;

  const f16* zn_hi = (const f16*)(ws + WS_ZN_HI);
  const f16* cb_hi = (const f16*)(ws + WS_CB_HI);

  const int reg = w >> 1;            // 0 = stage A, 1 = stage B
  const int half = w & 1;            // which 64-row half of the tile
  // pre-swizzled global source: LDS[row][slot] holds granule (slot ^ (row&7))
  const int g0 = (lane & 7) ^ ((lane >> 3) & 7);
  const size_t laneOff = (size_t)(lane >> 3) * DIM + (size_t)g0 * 8;
  const f16* srcA0 = zn_hi + (size_t)(rowBase + half * 64) * DIM + laneOff;
  const f16* srcB0 = cb_hi + ((size_t)st * KCB + half * 64) * DIM + laneOff;

  f16* dst0 = reg ? &B0[half * 64][0] : &A0[half * 64][0];
  f16* dst1 = reg ? &B1[half * 64][0] : &A1[half * 64][0];

  float t1[16], t2[16]; int i1[16];
#pragma unroll
  for (int s = 0; s < 16; ++s) { t1[s] = -3.4e38f; t2[s] = -3.4e38f; i1[s] = 0; }
  const int colLane = wc * 64 + (lane & 15);

  // per-wave global source for slice (ct, dc)
  auto SRC = [&](int ct, int dc) -> const f16* {
    return reg ? (srcB0 + (size_t)ct * 128 * DIM + dc * 64) : (srcA0 + dc * 64);
  };
  auto STAGE = [&](f16* dst, const f16* sp) {
#pragma unroll
    for (int op = 0; op < 8; ++op)
      gll16(sp + op * 8 * DIM, dst + op * 512);
  };

  f32x4 acc[4][4];
  const f32x4 zero4 = {0.f, 0.f, 0.f, 0.f};

  // one phase: read frags (ds_read) -> stage next slice (gll16) -> MFMA -> barrier
  auto PHASE = [&](const f16* As, const f16* Bs, f16* stDst, const f16* stSrc,
                   bool doStage, bool init) {
    f16x8 ah[2][4], bh[2][4];
#pragma unroll
    for (int kk = 0; kk < 2; ++kk) {
#pragma unroll
      for (int m = 0; m < 4; ++m) {
        const int rl = wr * 64 + m * 16 + (lane & 15);
        const int slot = ((kk << 2) + (lane >> 4)) ^ (rl & 7);
        ah[kk][m] = *(const f16x8*)(As + rl * 64 + slot * 8);
      }
#pragma unroll
      for (int n = 0; n < 4; ++n) {
        const int cl = wc * 64 + n * 16 + (lane & 15);
        const int slot = ((kk << 2) + (lane >> 4)) ^ (cl & 7);
        bh[kk][n] = *(const f16x8*)(Bs + cl * 64 + slot * 8);
      }
    }
    if (doStage) STAGE(stDst, stSrc);
#pragma unroll
    for (int kk = 0; kk < 2; ++kk)
#pragma unroll
      for (int n = 0; n < 4; ++n) {
        if (init && kk == 0) {
#pragma unroll
          for (int m = 0; m < 4; ++m)
            acc[m][n] = __builtin_amdgcn_mfma_f32_16x16x32_f16(ah[0][m], bh[0][n], zero4, 0, 0, 0);
        } else {
#pragma unroll
          for (int m = 0; m < 4; ++m)
            acc[m][n] = __builtin_amdgcn_mfma_f32_16x16x32_f16(ah[kk][m], bh[kk][n], acc[m][n], 0, 0, 0);
        }
      }
    __syncthreads();
  };

  STAGE(dst0, SRC(0, 0));
  __syncthreads();   // drain prologue stage

  for (int ct = 0; ct < 32; ++ct) {
    PHASE(&A0[0][0], &B0[0][0], dst1, SRC(ct, 1), true, true);         // dc0
    PHASE(&A1[0][0], &B1[0][0], dst0, SRC(ct, 2), true, false);        // dc1
    PHASE(&A0[0][0], &B0[0][0], dst1, SRC(ct, 3), true, false);        // dc2
    PHASE(&A1[0][0], &B1[0][0], dst0, SRC(ct + 1, 0), ct < 31, false); // dc3
    // rank by raw dot (codebook unit-norm => ssq const to ~1e-7 << margin)
#pragma unroll
    for (int n = 0; n < 4; ++n) {
      const int col = ct * 128 + n * 16 + colLane;
#pragma unroll
      for (int m = 0; m < 4; ++m)
#pragma unroll
        for (int rr = 0; rr < 4; ++rr) {
          const float sc = acc[m][n][rr];
          const int sl = m * 4 + rr;
          if (sc > t1[sl]) { t2[sl] = t1[sl]; t1[sl] = sc; i1[sl] = col; }
          else t2[sl] = fmaxf(t2[sl], sc);
        }
    }
  }

  // epilogue: butterfly within 16-lane groups, then cross-half merge in LDS
  float* mv1 = (float*)&A0[0][0];  // [2][128], aliases dead buffer
  float* mv2 = mv1 + 256;
  int*   mi1v = (int*)(mv2 + 256);
#pragma unroll
  for (int m = 0; m < 4; ++m)
#pragma unroll
    for (int rr = 0; rr < 4; ++rr) {
      const int sl = m * 4 + rr;
      float a1 = t1[sl], a2 = t2[sl]; int ai = i1[sl];
#pragma unroll
      for (int msk = 1; msk < 16; msk <<= 1) {
        const float o1 = __shfl_xor(a1, msk);
        const float o2 = __shfl_xor(a2, msk);
        const int   oi = __shfl_xor(ai, msk);
        if (o1 > a1)       { a2 = fmaxf(a1, o2); a1 = o1; ai = oi; }
        else if (o1 == a1) { a2 = a1; ai = min(ai, oi); }
        else               { a2 = fmaxf(a2, o1); }
      }
      if ((lane & 15) == 0) {
        const int rloc = wr * 64 + m * 16 + (lane >> 4) * 4 + rr;
        mv1[wc * 128 + rloc] = a1; mv2[wc * 128 + rloc] = a2; mi1v[wc * 128 + rloc] = ai;
      }
    }
  __syncthreads();
  if (tid < 128) {
    const float a1 = mv1[tid], a2 = mv2[tid]; const int ai = mi1v[tid];
    const float b1 = mv1[128 + tid], b2 = mv2[128 + tid]; const int bi = mi1v[128 + tid];
    float v1, v2; int fi;
    if (a1 > b1)      { v1 = a1; v2 = fmaxf(a2, b1); fi = ai; }
    else if (b1 > a1) { v1 = b1; v2 = fmaxf(b2, a1); fi = bi; }
    else { v1 = a1; v2 = a1; fi = min(ai, bi); }
    const int row = rowBase + tid;
    ((int*)(ws + WS_IDX))[row * 4 + st] = fi;
    if (v1 - v2 < MARGIN_DOT) {
      const int p = atomicAdd((int*)(ws + WS_CNT) + st, 1);
      if (p < CAPL) ((int*)(ws + WS_LIST))[st * CAPL + p] = row;
      else {  // overflow valve: route straight to exact full-scan (no drop)
        const int p2 = atomicAdd((int*)(ws + WS_CNT) + 4 + st, 1);
        ((int*)(ws + WS_LIST2))[(size_t)st * NR + p2] = row;
      }
    }
  }
}

// ---- MFMA rescue: gather flagged rows, 3-pass hi/lo scan, 16 K-chunks ----
__launch_bounds__(256, 2)
__global__ void rescue_mfma_kernel(char* __restrict__ ws) {
  // [0]=A_hi [1]=A_lo [2]=B_hi [3]=B_lo, each [128 rows][64 halfs] = 64 KB
  __shared__ __align__(16) f16 smem[4][128][64];
  __shared__ float mv1[2][128], mv2[2][128];
  __shared__ int   mi1[2][128];
  const int tid = threadIdx.x, w = tid >> 6, lane = tid & 63;
  const int wr = w >> 1, wc = w & 1;
  const int st = blockIdx.x & 3;
  const int kc = (blockIdx.x >> 2) & 15;    // K-chunk: ct in [kc*2, kc*2+2)
  const int slot = blockIdx.x >> 6;         // 0..31 tile slot
  const int cnt = min(((const int*)(ws + WS_CNT))[st], CAPL);
  const int ntile = (cnt + 127) >> 7;
  const int* list = (const int*)(ws + WS_LIST) + st * CAPL;

  const f16* zn_hi = (const f16*)(ws + WS_ZN_HI);
  const f16* zn_lo = (const f16*)(ws + WS_ZN_LO);
  const f16* cb_hi = (const f16*)(ws + WS_CB_HI);
  const f16* cb_lo = (const f16*)(ws + WS_CB_LO);

  const int g0 = (lane & 7) ^ ((lane >> 3) & 7);
  const size_t laneOff = (size_t)(lane >> 3) * DIM + (size_t)g0 * 8;
  f16* ldsW = &smem[w][0][0];
  const f16* srcA = (w == 1) ? zn_lo : zn_hi;   // waves 0/1 stage A hi/lo
  const f16* srcB = (w == 3) ? cb_lo : cb_hi;   // waves 2/3 stage B hi/lo
  const int colLane = wc * 64 + (lane & 15);

  for (int tile = slot; tile < ntile; tile += 32) {
    const int base = tile << 7;
    int lid[16];
    if (w < 2) {
#pragma unroll
      for (int op = 0; op < 16; ++op) {
        const int i = base + op * 8 + (lane >> 3);
        lid[op] = list[min(i, cnt - 1)];
      }
    }
    float t1[16], t2[16]; int i1[16];
#pragma unroll
    for (int s = 0; s < 16; ++s) { t1[s] = -3.4e38f; t2[s] = -3.4e38f; i1[s] = 0; }

    for (int ct = kc * 2; ct < kc * 2 + 2; ++ct) {
      f32x4 acc[4][4];
#pragma unroll
      for (int m = 0; m < 4; ++m)
#pragma unroll
        for (int n = 0; n < 4; ++n) { acc[m][n][0] = 0.f; acc[m][n][1] = 0.f; acc[m][n][2] = 0.f; acc[m][n][3] = 0.f; }

      const f16* srcBBase = srcB + ((size_t)st * KCB + (size_t)ct * 128) * DIM + laneOff;

      for (int dc = 0; dc < 4; ++dc) {
        __syncthreads();
        if (w < 2) {
#pragma unroll
          for (int op = 0; op < 16; ++op)
            gll16(srcA + (size_t)lid[op] * DIM + dc * 64 + (size_t)g0 * 8,
                  ldsW + op * 512);
        } else {
          const f16* sp = srcBBase + dc * 64;
#pragma unroll
          for (int op = 0; op < 16; ++op)
            gll16(sp + op * 8 * DIM, ldsW + op * 512);
        }
        __syncthreads();

#pragma unroll
        for (int kk = 0; kk < 2; ++kk) {
          f16x8 ah[4], al[4];
#pragma unroll
          for (int m = 0; m < 4; ++m) {
            const int rl = wr * 64 + m * 16 + (lane & 15);
            const int slt = ((kk << 2) + (lane >> 4)) ^ (rl & 7);
            const int off = rl * 64 + slt * 8;
            ah[m] = *(const f16x8*)(&smem[0][0][0] + off);
            al[m] = *(const f16x8*)(&smem[1][0][0] + off);
          }
#pragma unroll
          for (int n = 0; n < 4; ++n) {
            const int cl = wc * 64 + n * 16 + (lane & 15);
            const int slt = ((kk << 2) + (lane >> 4)) ^ (cl & 7);
            const int off = cl * 64 + slt * 8;
            const f16x8 bh = *(const f16x8*)(&smem[2][0][0] + off);
            const f16x8 bl = *(const f16x8*)(&smem[3][0][0] + off);
#pragma unroll
            for (int m = 0; m < 4; ++m) {
              acc[m][n] = __builtin_amdgcn_mfma_f32_16x16x32_f16(ah[m], bh, acc[m][n], 0, 0, 0);
              acc[m][n] = __builtin_amdgcn_mfma_f32_16x16x32_f16(ah[m], bl, acc[m][n], 0, 0, 0);
              acc[m][n] = __builtin_amdgcn_mfma_f32_16x16x32_f16(al[m], bh, acc[m][n], 0, 0, 0);
            }
          }
        }
      }
#pragma unroll
      for (int n = 0; n < 4; ++n) {
        const int col = ct * 128 + n * 16 + colLane;
#pragma unroll
        for (int m = 0; m < 4; ++m)
#pragma unroll
          for (int r = 0; r < 4; ++r) {
            const float sc = acc[m][n][r];
            const int sl = m * 4 + r;
            if (sc > t1[sl]) { t2[sl] = t1[sl]; t1[sl] = sc; i1[sl] = col; }
            else t2[sl] = fmaxf(t2[sl], sc);
          }
      }
    }

    // butterfly merge across 16 lanes -> LDS merge buffers
#pragma unroll
    for (int m = 0; m < 4; ++m)
#pragma unroll
      for (int r = 0; r < 4; ++r) {
        const int sl = m * 4 + r;
        float a1 = t1[sl], a2 = t2[sl]; int ai = i1[sl];
#pragma unroll
        for (int msk = 1; msk < 16; msk <<= 1) {
          const float o1 = __shfl_xor(a1, msk);
          const float o2 = __shfl_xor(a2, msk);
          const int   oi = __shfl_xor(ai, msk);
          if (o1 > a1)       { a2 = fmaxf(a1, o2); a1 = o1; ai = oi; }
          else if (o1 == a1) { a2 = a1; ai = min(ai, oi); }
          else               { a2 = fmaxf(a2, o1); }
        }
        if ((lane & 15) == 0) {
          const int rloc = wr * 64 + m * 16 + (lane >> 4) * 4 + r;
          mv1[wc][rloc] = a1; mv2[wc][rloc] = a2; mi1[wc][rloc] = ai;
        }
      }
    __syncthreads();
    if (tid < 128 && base + tid < cnt) {
      const float a1 = mv1[0][tid], a2 = mv2[0][tid]; const int ai = mi1[0][tid];
      const float b1 = mv1[1][tid], b2 = mv2[1][tid]; const int bi = mi1[1][tid];
      float v1, v2; int fi;
      if (a1 > b1)      { v1 = a1; v2 = fmaxf(a2, b1); fi = ai; }
      else if (b1 > a1) { v1 = b1; v2 = fmaxf(b2, a1); fi = bi; }
      else { v1 = a1; v2 = a1; fi = min(ai, bi); }
      ((float4*)(ws + WS_TOPS2))[((size_t)(st * CAPL + base + tid) << 4) + kc] =
          make_float4(v1, v2, __int_as_float(fi), 0.f);
    }
    __syncthreads();
  }
}

// ---- merge 16 K-chunk partials per flagged row, flag ultra-ties ----
__global__ void rescue_merge_kernel(char* __restrict__ ws) {
  const int t = blockIdx.x * 256 + threadIdx.x;   // 4*CAPL entries
  const int st = t >> 12, j = t & (CAPL - 1);
  const int cnt = min(((const int*)(ws + WS_CNT))[st], CAPL);
  if (j >= cnt) return;
  const float4* p = (const float4*)(ws + WS_TOPS2) + ((size_t)(st * CAPL + j) << 4);
  float V1 = -3.4e38f, V2 = -3.4e38f; int I1 = 0;
#pragma unroll
  for (int c = 0; c < 16; ++c) {
    const float4 e = p[c];
    const float v1 = e.x, v2 = e.y; const int i1 = __float_as_int(e.z);
    if (v1 > V1) { V2 = fmaxf(V1, v2); V1 = v1; I1 = i1; }
    else {
      if (v1 == V1) I1 = min(I1, i1);
      V2 = fmaxf(V2, v1);
    }
  }
  const int row = ((const int*)(ws + WS_LIST))[st * CAPL + j];
  ((int*)(ws + WS_IDX))[row * 4 + st] = I1;
  if (V1 - V2 < MARGIN2_DOT) {
    const int p2 = atomicAdd((int*)(ws + WS_CNT) + 4 + st, 1);
    ((int*)(ws + WS_LIST2))[(size_t)st * NR + p2] = row;
  }
}

// ---- parallel exact fp32 chain-dot scan: one code/thread, 16 K-chunks ----
__global__ void rescue_exact_kernel(const float* __restrict__ x, const float* __restrict__ cb,
                                    char* __restrict__ ws) {
  __shared__ __align__(16) float zrow[DIM];
  __shared__ float zsq_s;
  __shared__ float lbv[4];
  __shared__ int   lbi[4];
  const int tid = threadIdx.x, w = tid >> 6, lane = tid & 63;
  const int st = blockIdx.x & 3;
  const int kc = (blockIdx.x >> 2) & 15;    // 16 K-chunks of 256 codes
  const int slot = blockIdx.x >> 6;         // 16 row slots
  const int cnt = min(((const int*)(ws + WS_CNT))[4 + st], CAPL);
  const int* list = (const int*)(ws + WS_LIST2) + (size_t)st * NR;
  const float* cbs = cb + (size_t)st * KCB * DIM;
  const float* ssqp = (const float*)(ws + WS_SSQ) + (size_t)st * KCB;
  int2* part = (int2*)(ws + WS_TOPS3);

  for (int j = slot; j < cnt; j += 16) {
    const int row = list[j];
    if (tid < 32) {
      const float denom = ((const float*)(ws + WS_NORMS))[row];
      const int g = tid;
      float ss = 0.f;
#pragma unroll
      for (int e = 0; e < 8; ++e) {
        const float v = x[(size_t)row * DIM + g * 8 + e] / denom;
        zrow[g * 8 + e] = v;
        ss += v * v;
      }
#pragma unroll
      for (int m = 16; m; m >>= 1) ss += __shfl_xor(ss, m);
      if (g == 0) zsq_s = ss;
    }
    __syncthreads();
    const float zsq = zsq_s;
    const int k = kc * 256 + tid;
    const float dot = dot4chain((const float4*)(cbs + (size_t)k * DIM), (const float4*)zrow);
    float bd = (zsq + ssqp[k]) - 2.0f * dot;
    int bi = k;
#pragma unroll
    for (int m = 32; m; m >>= 1) {
      const float od = __shfl_xor(bd, m);
      const int   oi = __shfl_xor(bi, m);
      if (od < bd || (od == bd && oi < bi)) { bd = od; bi = oi; }
    }
    if (lane == 0) { lbv[w] = bd; lbi[w] = bi; }
    __syncthreads();
    if (tid == 0) {
      float fb = lbv[0]; int fi = lbi[0];
#pragma unroll
      for (int ww = 1; ww < 4; ++ww)
        if (lbv[ww] < fb || (lbv[ww] == fb && lbi[ww] < fi)) { fb = lbv[ww]; fi = lbi[ww]; }
      part[((size_t)(st * CAPL + j) << 4) + kc] = make_int2(__float_as_int(fb), fi);
    }
    __syncthreads();
  }
}

// ---- fold 16 K-chunk partials per ultra-tie row ----
__global__ void rescue_exact_merge_kernel(char* __restrict__ ws) {
  const int t = blockIdx.x * 256 + threadIdx.x;   // 4*CAPL entries
  const int st = t >> 12, j = t & (CAPL - 1);
  const int cnt = min(((const int*)(ws + WS_CNT))[4 + st], CAPL);
  if (j >= cnt) return;
  const int2* part = (const int2*)(ws + WS_TOPS3) + ((size_t)(st * CAPL + j) << 4);
  float fb = 3.4e38f; int fi = 0x7fffffff;
#pragma unroll
  for (int kc = 0; kc < 16; ++kc) {
    const int2 e = part[kc];
    const float d = __int_as_float(e.x);
    if (d < fb || (d == fb && e.y < fi)) { fb = d; fi = e.y; }
  }
  const int row = ((const int*)(ws + WS_LIST2))[(size_t)st * NR + j];
  ((int*)(ws + WS_IDX))[row * 4 + st] = fi;
}

// ---- serial tail valve: ultra-tie rows beyond CAPL (empty in practice) ----
__global__ void rescue_tail_kernel(const float* __restrict__ x, const float* __restrict__ cb,
                                   char* __restrict__ ws) {
  __shared__ __align__(16) float zrows[8][DIM];
  __shared__ float zsqs[8];
  __shared__ float lbv[4][8];
  __shared__ int   lbi[4][8];
  const int tid = threadIdx.x, w = tid >> 6, lane = tid & 63;
  const int st = blockIdx.x & 3, slot = blockIdx.x >> 2;   // 16 slots/stage
  const int cnt = ((const int*)(ws + WS_CNT))[4 + st] - CAPL;
  if (cnt <= 0) return;
  const int nch = (cnt + 7) >> 3;
  const int* list = (const int*)(ws + WS_LIST2) + (size_t)st * NR + CAPL;
  const float* cbs = cb + (size_t)st * KCB * DIM;
  const float* ssqp = (const float*)(ws + WS_SSQ) + (size_t)st * KCB;

  for (int ch = slot; ch < nch; ch += 16) {
    const int base = ch * 8;
    const int nr = min(8, cnt - base);
    const int r = tid >> 5, g = tid & 31;
    if (r < nr) {
      const int row = list[base + r];
      const float denom = ((const float*)(ws + WS_NORMS))[row];
      float ss = 0.f;
#pragma unroll
      for (int j = 0; j < 8; ++j) {
        const float v = x[(size_t)row * DIM + g * 8 + j] / denom;
        zrows[r][g * 8 + j] = v;
        ss += v * v;
      }
#pragma unroll
      for (int m = 16; m; m >>= 1) ss += __shfl_xor(ss, m);
      if (g == 0) zsqs[r] = ss;
    }
    __syncthreads();

    float bd[8]; int bix[8];
#pragma unroll
    for (int q = 0; q < 8; ++q) { bd[q] = 3.4e38f; bix[q] = 0x7fffffff; }

    for (int k = tid; k < KCB; k += 256) {
      const float4* cr = (const float4*)(cbs + (size_t)k * DIM);
      const float4* zr = (const float4*)&zrows[0][0];
      float dot[8];
#pragma unroll
      for (int q = 0; q < 8; ++q) dot[q] = 0.f;
      for (int d = 0; d < 64; ++d) {
        const float4 cv = cr[d];
#pragma unroll
        for (int q = 0; q < 8; ++q) {
          const float4 zv = zr[q * 64 + d];
          dot[q] += cv.x * zv.x + cv.y * zv.y + cv.z * zv.z + cv.w * zv.w;
        }
      }
      const float sk = ssqp[k];
#pragma unroll
      for (int q = 0; q < 8; ++q) {
        const float dist = (zsqs[q] + sk) - 2.0f * dot[q];
        if (dist < bd[q]) { bd[q] = dist; bix[q] = k; }
      }
    }
#pragma unroll
    for (int q = 0; q < 8; ++q) {
#pragma unroll
      for (int m = 32; m; m >>= 1) {
        const float od = __shfl_xor(bd[q], m);
        const int   oi = __shfl_xor(bix[q], m);
        if (od < bd[q] || (od == bd[q] && oi < bix[q])) { bd[q] = od; bix[q] = oi; }
      }
      if (lane == 0) { lbv[w][q] = bd[q]; lbi[w][q] = bix[q]; }
    }
    __syncthreads();
    if (tid < 8 && tid < nr) {
      float fb = lbv[0][tid]; int fi = lbi[0][tid];
#pragma unroll
      for (int ww = 1; ww < 4; ++ww) {
        const float od = lbv[ww][tid]; const int oi = lbi[ww][tid];
        if (od < fb || (od == fb && oi < fi)) { fb = od; fi = oi; }
      }
      const int row = list[base + tid];
      ((int*)(ws + WS_IDX))[row * 4 + st] = fi;
    }
    __syncthreads();
  }
}

// ---- gather codewords, quantized sum, loss partials, indices(as float) ----
__global__ void finalize_kernel(const float* __restrict__ x, const float* __restrict__ cb,
                                char* __restrict__ ws, float* __restrict__ out) {
  __shared__ float wsum[4];
  const int w = threadIdx.x >> 6, lane = threadIdx.x & 63;
  const int row = blockIdx.x * 4 + w;
  const int* idxp = (const int*)(ws + WS_IDX) + (size_t)row * 4;
  const float denom = ((const float*)(ws + WS_NORMS))[row];
  const float4 xv = ((const float4*)x)[row * 64 + lane];
  const float4 zn = make_float4(xv.x / denom, xv.y / denom, xv.z / denom, xv.w / denom);
  float4 s = make_float4(0.f, 0.f, 0.f, 0.f);
  float lacc = 0.f;
#pragma unroll
  for (int q = 0; q < 4; ++q) {
    const int id = idxp[q];
    const float4 e = ((const float4*)(cb + ((size_t)q * KCB + id) * DIM))[lane];
    s.x += e.x; s.y += e.y; s.z += e.z; s.w += e.w;
    const float dx = e.x - zn.x, dy = e.y - zn.y, dz = e.z - zn.z, dw = e.w - zn.w;
    lacc += dx * dx + dy * dy + dz * dz + dw * dw;
  }
  ((float4*)out)[row * 64 + lane] = s;
  if (lane < 4) out[4194305 + (size_t)row * 4 + lane] = (float)idxp[lane];
#pragma unroll
  for (int m = 32; m; m >>= 1) lacc += __shfl_xor(lacc, m);
  if (lane == 0) wsum[w] = lacc;
  __syncthreads();
  if (threadIdx.x == 0)
    ((float*)(ws + WS_PART))[blockIdx.x] = wsum[0] + wsum[1] + wsum[2] + wsum[3];
}

__global__ void loss_final_kernel(const char* __restrict__ ws, float* __restrict__ out) {
  __shared__ float wsum[4];
  const int tid = threadIdx.x, w = tid >> 6, lane = tid & 63;
  const float* p = (const float*)(ws + WS_PART);
  float s = 0.f;
  for (int i = tid; i < 4096; i += 256) s += p[i];
#pragma unroll
  for (int m = 32; m; m >>= 1) s += __shfl_xor(s, m);
  if (lane == 0) wsum[w] = s;
  __syncthreads();
  if (tid == 0)
    out[4194304] = (wsum[0] + wsum[1] + wsum[2] + wsum[3]) * (1.0f / 4194304.0f);
}

extern "C" void kernel_launch(void* const* d_in, const int* in_sizes, int n_in,
                              void* d_out, int out_size, void* d_ws, size_t ws_size,
                              hipStream_t stream) {
  (void)in_sizes; (void)n_in; (void)out_size; (void)ws_size;
  const float* x = (const float*)d_in[0];
  const float* cb = (const float*)d_in[1];
  float* out = (float*)d_out;
  char* ws = (char*)d_ws;

  hipLaunchKernelGGL(prep_kernel, dim3(NR / 2), dim3(256), 0, stream, x, cb, ws);
  hipLaunchKernelGGL(score_kernel, dim3(512), dim3(256), 0, stream, ws);
  hipLaunchKernelGGL(rescue_mfma_kernel, dim3(2048), dim3(256), 0, stream, ws);
  hipLaunchKernelGGL(rescue_merge_kernel, dim3((QST * CAPL) / 256), dim3(256), 0, stream, ws);
  hipLaunchKernelGGL(rescue_exact_kernel, dim3(1024), dim3(256), 0, stream, x, cb, ws);
  hipLaunchKernelGGL(rescue_exact_merge_kernel, dim3((QST * CAPL) / 256), dim3(256), 0, stream, ws);
  hipLaunchKernelGGL(rescue_tail_kernel, dim3(64), dim3(256), 0, stream, x, cb, ws);
  hipLaunchKernelGGL(finalize_kernel, dim3(NR / 4), dim3(256), 0, stream, x, cb, ws, out);
  hipLaunchKernelGGL(loss_final_kernel, dim3(1), dim3(256), 0, stream, ws, out);
}